// Round 1
// baseline (154.267 us; speedup 1.0000x reference)
//
#include <hip/hip_runtime.h>

// Sliding 79x69 box-filter mean, SAME zero padding, then (x - mean) / 5.
// Separable: vertical 79-tap sliding sum -> horizontal 69-tap sum via
// wave-level prefix scan (no LDS, no barriers).

#define HH   512
#define WW   512
#define NIMG 32
#define RH   39   // (79-1)/2
#define RW   34   // (69-1)/2
#define CHUNK 64
#define NCHUNK (HH / CHUNK)

// ---------------------------------------------------------------------------
// Pass 1: vertical sliding sum. Thread = (n, chunk, w). Lanes = consecutive w
// -> coalesced 256B wave transactions down the column.
// ---------------------------------------------------------------------------
__global__ __launch_bounds__(256) void vpass_kernel(const float* __restrict__ x,
                                                    float* __restrict__ colsum) {
    int t = blockIdx.x * 256 + threadIdx.x;
    int w = t & (WW - 1);
    int c = (t >> 9) & (NCHUNK - 1);
    int n = t >> 12;

    const float* p = x      + (size_t)n * HH * WW + w;
    float*       q = colsum + (size_t)n * HH * WW + w;

    int h0 = c * CHUNK;
    float s = 0.0f;
    int lo = h0 - RH; if (lo < 0) lo = 0;
    int hi = h0 + RH; if (hi > HH - 1) hi = HH - 1;
    for (int i = lo; i <= hi; ++i) s += p[(size_t)i * WW];

    #pragma unroll 4
    for (int h = h0; h < h0 + CHUNK; ++h) {
        q[(size_t)h * WW] = s;
        int ia = h + RH + 1;   // enters window for h+1
        int ib = h - RH;       // leaves window for h+1
        if (ia < HH) s += p[(size_t)ia * WW];
        if (ib >= 0) s -= p[(size_t)ib * WW];
    }
}

// ---------------------------------------------------------------------------
// Pass 2: horizontal 69-tap sum via per-wave prefix scan + finalize.
// One wave (64 lanes) per image row; lane holds 8 contiguous elements.
// rowsum[w] = P[min(512, w+35)] - P[max(0, w-34)]  (P = exclusive prefix)
// ---------------------------------------------------------------------------
__global__ __launch_bounds__(256) void hpass_kernel(const float* __restrict__ colsum,
                                                    const float* __restrict__ x,
                                                    float* __restrict__ out) {
    const float INV = 1.0f / (79.0f * 69.0f);

    int gid  = blockIdx.x * 256 + threadIdx.x;
    int row  = gid >> 6;             // 0 .. NIMG*HH-1
    int lane = threadIdx.x & 63;

    size_t base = (size_t)row * WW;

    const float4* tp = (const float4*)(colsum + base);
    float4 a0 = tp[lane * 2];
    float4 a1 = tp[lane * 2 + 1];

    // in-register inclusive prefix of this lane's 8 elements
    float p[8];
    p[0] = a0.x;        p[1] = p[0] + a0.y;
    p[2] = p[1] + a0.z; p[3] = p[2] + a0.w;
    p[4] = p[3] + a1.x; p[5] = p[4] + a1.y;
    p[6] = p[5] + a1.z; p[7] = p[6] + a1.w;

    // wave-inclusive scan of lane totals
    float s = p[7];
    #pragma unroll
    for (int d = 1; d < 64; d <<= 1) {
        float t2 = __shfl_up(s, d, 64);
        if (lane >= d) s += t2;
    }
    float offset = s - p[7];         // exclusive offset for this lane

    float pf[8];                     // pf[j] = P[lane*8 + j + 1]
    #pragma unroll
    for (int j = 0; j < 8; ++j) pf[j] = offset + p[j];

    float total = __shfl(pf[7], 63, 64);   // P[512]

    const float4* xp = (const float4*)(x + base);
    float4 b0 = xp[lane * 2];
    float4 b1 = xp[lane * 2 + 1];
    float xv[8] = { b0.x, b0.y, b0.z, b0.w, b1.x, b1.y, b1.z, b1.w };

    float o[8];
    #pragma unroll
    for (int j = 0; j < 8; ++j) {
        // hi endpoint: P[w+RW+1], stored at lane l + (j+RW)/8, slot (j+RW)%8
        int hidx = j + RW;                 // 34..41
        int dhi  = hidx >> 3;              // 4 or 5
        int shi  = hidx & 7;
        float hv = __shfl_down(pf[shi], dhi, 64);
        if (lane + dhi > 63) hv = total;   // w+35 > 512 -> P[512]

        // lo endpoint: P[w-RW], stored at lane l + floor((j-RW-1)/8)
        int lidx = j - RW - 1;             // -35..-28
        int fl   = lidx >> 3;              // -5 or -4 (arithmetic shift = floor)
        int dlo  = -fl;
        int slo  = lidx - fl * 8;          // 0..7
        float lv = __shfl_up(pf[slo], dlo, 64);
        if (lane < dlo) lv = 0.0f;         // w-34 <= 0 -> P[0] = 0

        float mean = (hv - lv) * INV;
        o[j] = (xv[j] - mean) * 0.2f;
    }

    float4* op = (float4*)(out + base);
    op[lane * 2]     = make_float4(o[0], o[1], o[2], o[3]);
    op[lane * 2 + 1] = make_float4(o[4], o[5], o[6], o[7]);
}

extern "C" void kernel_launch(void* const* d_in, const int* in_sizes, int n_in,
                              void* d_out, int out_size, void* d_ws, size_t ws_size,
                              hipStream_t stream) {
    const float* x   = (const float*)d_in[0];
    float*       out = (float*)d_out;
    float*       tmp = (float*)d_ws;   // needs NIMG*HH*WW*4 = 32 MiB scratch

    int vthreads = NIMG * WW * NCHUNK;            // 131072
    vpass_kernel<<<vthreads / 256, 256, 0, stream>>>(x, tmp);

    int hthreads = NIMG * HH * 64;                // 1048576
    hpass_kernel<<<hthreads / 256, 256, 0, stream>>>(tmp, x, out);
}

// Round 2
// 116.613 us; speedup vs baseline: 1.3229x; 1.3229x over previous
//
#include <hip/hip_runtime.h>

// Sliding 79x69 box-filter mean, SAME zero padding, then (x - mean) / 5.
// Separable: vertical 79-tap sliding sum (float4, ILP-heavy) -> horizontal
// 69-tap sum via wave-level prefix scan (no LDS, no barriers).

#define HH   512
#define WW   512
#define NIMG 32
#define RH   39   // (79-1)/2
#define RW   34   // (69-1)/2
#define CHUNK 16
#define NCHUNK (HH / CHUNK)   // 32
#define W4 (WW / 4)           // 128 float4 per row

__device__ __forceinline__ float4 add4(float4 a, float4 b) {
    return make_float4(a.x + b.x, a.y + b.y, a.z + b.z, a.w + b.w);
}
__device__ __forceinline__ float4 sub4(float4 a, float4 b) {
    return make_float4(a.x - b.x, a.y - b.y, a.z - b.z, a.w - b.w);
}

// ---------------------------------------------------------------------------
// Pass 1: vertical sliding sum. Thread = (n, chunk16, w4). float4 per lane,
// 4 partial accumulators in the 79-row prologue for ILP; interior chunks
// take a fully-unrolled check-free path.
// ---------------------------------------------------------------------------
__global__ __launch_bounds__(256) void vpass_kernel(const float* __restrict__ xg,
                                                    float* __restrict__ cg) {
    int t  = blockIdx.x * 256 + threadIdx.x;
    int w4 = t & (W4 - 1);
    int c  = (t >> 7) & (NCHUNK - 1);
    int n  = t >> 12;

    const float4* p = (const float4*)xg + (size_t)n * HH * W4 + w4;
    float4*       q = (float4*)cg       + (size_t)n * HH * W4 + w4;
    int h0 = c * CHUNK;

    if (h0 - RH >= 0 && h0 + CHUNK + RH <= HH) {
        // interior: rows [h0-39, h0+55] all in range
        const float4* pr = p + (size_t)(h0 - RH) * W4;
        float4 s0 = make_float4(0, 0, 0, 0), s1 = s0, s2 = s0, s3 = s0;
        #pragma unroll
        for (int i = 0; i < 76; i += 4) {
            s0 = add4(s0, pr[(size_t)(i + 0) * W4]);
            s1 = add4(s1, pr[(size_t)(i + 1) * W4]);
            s2 = add4(s2, pr[(size_t)(i + 2) * W4]);
            s3 = add4(s3, pr[(size_t)(i + 3) * W4]);
        }
        s0 = add4(s0, pr[(size_t)76 * W4]);
        s1 = add4(s1, pr[(size_t)77 * W4]);
        s2 = add4(s2, pr[(size_t)78 * W4]);
        float4 s = add4(add4(s0, s1), add4(s2, s3));
        #pragma unroll
        for (int h = h0; h < h0 + CHUNK; ++h) {
            q[(size_t)h * W4] = s;
            s = add4(s, p[(size_t)(h + RH + 1) * W4]);
            s = sub4(s, p[(size_t)(h - RH) * W4]);
        }
    } else {
        int lo = h0 - RH; if (lo < 0) lo = 0;
        int hi = h0 + RH; if (hi > HH - 1) hi = HH - 1;
        float4 s0 = make_float4(0, 0, 0, 0), s1 = s0, s2 = s0, s3 = s0;
        int i = lo;
        for (; i + 4 <= hi + 1; i += 4) {
            s0 = add4(s0, p[(size_t)(i + 0) * W4]);
            s1 = add4(s1, p[(size_t)(i + 1) * W4]);
            s2 = add4(s2, p[(size_t)(i + 2) * W4]);
            s3 = add4(s3, p[(size_t)(i + 3) * W4]);
        }
        for (; i <= hi; ++i) s0 = add4(s0, p[(size_t)i * W4]);
        float4 s = add4(add4(s0, s1), add4(s2, s3));
        #pragma unroll
        for (int h = h0; h < h0 + CHUNK; ++h) {
            q[(size_t)h * W4] = s;
            int ia = h + RH + 1, ib = h - RH;
            if (ia < HH) s = add4(s, p[(size_t)ia * W4]);
            if (ib >= 0) s = sub4(s, p[(size_t)ib * W4]);
        }
    }
}

// ---------------------------------------------------------------------------
// Pass 2: horizontal 69-tap sum via per-wave prefix scan + finalize.
// One wave (64 lanes) per image row; lane holds 8 contiguous elements.
// rowsum[w] = P[min(512, w+35)] - P[max(0, w-34)]  (P = exclusive prefix)
// ---------------------------------------------------------------------------
__global__ __launch_bounds__(256) void hpass_kernel(const float* __restrict__ colsum,
                                                    const float* __restrict__ x,
                                                    float* __restrict__ out) {
    const float INV = 1.0f / (79.0f * 69.0f);

    int gid  = blockIdx.x * 256 + threadIdx.x;
    int row  = gid >> 6;             // 0 .. NIMG*HH-1
    int lane = threadIdx.x & 63;

    size_t base = (size_t)row * WW;

    const float4* tp = (const float4*)(colsum + base);
    const float4* xp = (const float4*)(x + base);
    float4 a0 = tp[lane * 2];
    float4 a1 = tp[lane * 2 + 1];
    float4 b0 = xp[lane * 2];        // issued early: overlaps scan latency
    float4 b1 = xp[lane * 2 + 1];

    // in-register inclusive prefix of this lane's 8 elements
    float p[8];
    p[0] = a0.x;        p[1] = p[0] + a0.y;
    p[2] = p[1] + a0.z; p[3] = p[2] + a0.w;
    p[4] = p[3] + a1.x; p[5] = p[4] + a1.y;
    p[6] = p[5] + a1.z; p[7] = p[6] + a1.w;

    // wave-inclusive scan of lane totals
    float s = p[7];
    #pragma unroll
    for (int d = 1; d < 64; d <<= 1) {
        float t2 = __shfl_up(s, d, 64);
        if (lane >= d) s += t2;
    }
    float offset = s - p[7];         // exclusive offset for this lane

    float pf[8];                     // pf[j] = P[lane*8 + j + 1]
    #pragma unroll
    for (int j = 0; j < 8; ++j) pf[j] = offset + p[j];

    float total = __shfl(pf[7], 63, 64);   // P[512]

    float xv[8] = { b0.x, b0.y, b0.z, b0.w, b1.x, b1.y, b1.z, b1.w };

    float o[8];
    #pragma unroll
    for (int j = 0; j < 8; ++j) {
        // hi endpoint: P[w+RW+1] at lane l + (j+RW)/8, slot (j+RW)%8
        int hidx = j + RW;                 // 34..41
        int dhi  = hidx >> 3;              // 4 or 5
        int shi  = hidx & 7;
        float hv = __shfl_down(pf[shi], dhi, 64);
        if (lane + dhi > 63) hv = total;   // w+35 > 512 -> P[512]

        // lo endpoint: P[w-RW] at lane l + floor((j-RW-1)/8)
        int lidx = j - RW - 1;             // -35..-28
        int fl   = lidx >> 3;              // arithmetic shift = floor
        int dlo  = -fl;
        int slo  = lidx - fl * 8;          // 0..7
        float lv = __shfl_up(pf[slo], dlo, 64);
        if (lane < dlo) lv = 0.0f;         // w-34 <= 0 -> P[0] = 0

        float mean = (hv - lv) * INV;
        o[j] = (xv[j] - mean) * 0.2f;
    }

    float4* op = (float4*)(out + base);
    op[lane * 2]     = make_float4(o[0], o[1], o[2], o[3]);
    op[lane * 2 + 1] = make_float4(o[4], o[5], o[6], o[7]);
}

extern "C" void kernel_launch(void* const* d_in, const int* in_sizes, int n_in,
                              void* d_out, int out_size, void* d_ws, size_t ws_size,
                              hipStream_t stream) {
    const float* x   = (const float*)d_in[0];
    float*       out = (float*)d_out;
    float*       tmp = (float*)d_ws;   // needs NIMG*HH*WW*4 = 32 MiB scratch

    int vthreads = NIMG * NCHUNK * W4;            // 131072
    vpass_kernel<<<vthreads / 256, 256, 0, stream>>>(x, tmp);

    int hthreads = NIMG * HH * 64;                // 1048576
    hpass_kernel<<<hthreads / 256, 256, 0, stream>>>(tmp, x, out);
}